// Round 4
// baseline (982.920 us; speedup 1.0000x reference)
//
#include <hip/hip_runtime.h>
#include <math.h>

#define NNODES 100000
#define NEDGES 1600000
#define DF 128
#define ED 16
#define NBLK_SCAN ((NNODES + 255) / 256)   // 391

typedef float v2f __attribute__((ext_vector_type(2)));

// ---------------- prep: interleave layer1/layer2 edge-MLP params for packed math
// wint[j*32 + 2k + L] = wL[k*128 + j]   (j in [0,128), k in [0,16), L in {0,1})
// bw2[2j + L] = bL[j] ;  bw2[256 + 2j + L] = w2L[j]
__global__ void k_prep(const float* __restrict__ m1w1, const float* __restrict__ m2w1,
                       const float* __restrict__ m1b1, const float* __restrict__ m2b1,
                       const float* __restrict__ m1w2, const float* __restrict__ m2w2,
                       float* __restrict__ wint, float* __restrict__ bw2) {
    int t = blockIdx.x * blockDim.x + threadIdx.x;
    if (t < 4096) {
        int j = t >> 5, r = t & 31;
        int k = r >> 1, L = r & 1;
        const float* src = L ? m2w1 : m1w1;
        wint[t] = src[k * DF + j];
    } else if (t < 4096 + 256) {
        int i = t - 4096;
        int j = i >> 1, L = i & 1;
        bw2[i] = L ? m2b1[j] : m1b1[j];
    } else if (t < 4096 + 512) {
        int i = t - 4096 - 256;
        int j = i >> 1, L = i & 1;
        bw2[256 + i] = L ? m2w2[j] : m1w2[j];
    }
}

// ---------------- deg init (self-loop weight 1) + zero in-degree counters
__global__ void k_deg_init(float* __restrict__ d1, float* __restrict__ d2,
                           int* __restrict__ cnt) {
    int i = blockIdx.x * blockDim.x + threadIdx.x;
    if (i < NNODES) { d1[i] = 1.f; d2[i] = 1.f; cnt[i] = 0; }
}

// ---------------- edge gates, BOTH layers packed into v_pk_fma_f32 halves.
// v7: round-0 LDS layout + b64 weight broadcasts (measured 2.78 cyc/inst on
// the per-CU LDS pipe; b128 broadcasts cost ~13 cyc -- round-3 lesson: widen
// by EDGES PER THREAD, not by LDS word size). FOUR edges per thread: 18 b64
// LDS insts per j feed 4 edges (per-edge 36 -> 9 at the cheap rate).
// Arithmetic: LDS ~65us, VALU ~51us -> ~100-130us expected.
// Register budget: a[4][16]=64 + z/h/addr ~= 110 VGPR; plain launch_bounds
// (round-1's (256,4) cap caused the spill) + unroll 1 on the j loop.
__global__ __launch_bounds__(256) void k_gates7(
    const float* __restrict__ ea, const int* __restrict__ ei,
    const float* __restrict__ wint, const float* __restrict__ bw2,
    const float* __restrict__ b21, const float* __restrict__ b22,
    float* __restrict__ g1, float* __restrict__ g2,
    float* __restrict__ deg1, float* __restrict__ deg2,
    int* __restrict__ cnt) {
    __shared__ __align__(16) v2f sw[2048];          // 16 KB interleaved weights
    __shared__ __align__(16) v2f sb[128], s2[128];  // bias pairs, w2 pairs
    int t = threadIdx.x;
    for (int i = t; i < 2048; i += 256) sw[i] = ((const v2f*)wint)[i];
    if (t < 128) { sb[t] = ((const v2f*)bw2)[t]; s2[t] = ((const v2f*)(bw2 + 256))[t]; }
    __syncthreads();

    int e0 = blockIdx.x * 1024 + t;   // edges e0 + {0,256,512,768}

    float a[4][16];
#pragma unroll
    for (int i = 0; i < 4; i++) {
        int e = e0 + i * 256;
        if (e > NEDGES - 1) e = NEDGES - 1;   // clamp (tail block only)
        const float4* p4 = (const float4*)(ea + (size_t)e * ED);
#pragma unroll
        for (int q = 0; q < 4; q++) {
            float4 v = p4[q];
            a[i][q*4+0] = v.x; a[i][q*4+1] = v.y;
            a[i][q*4+2] = v.z; a[i][q*4+3] = v.w;
        }
    }

    v2f z[4];
    {
        v2f z0; z0.x = b21[0]; z0.y = b22[0];
#pragma unroll
        for (int i = 0; i < 4; i++) z[i] = z0;
    }

#pragma unroll 1
    for (int j = 0; j < 128; j++) {
        const v2f* wp = sw + j * 16;   // 16 x ds_read_b64 (uniform broadcast)
        v2f h0 = sb[j];
        v2f h1 = h0, h2 = h0, h3 = h0;
#pragma unroll
        for (int k = 0; k < 16; k++) {
            v2f q = wp[k];
            h0 += q * a[0][k];    // v_pk_fma_f32
            h1 += q * a[1][k];
            h2 += q * a[2][k];
            h3 += q * a[3][k];
        }
        v2f w2j = s2[j];
        z[0] += __builtin_elementwise_max(h0, (v2f)(0.f)) * w2j;
        z[1] += __builtin_elementwise_max(h1, (v2f)(0.f)) * w2j;
        z[2] += __builtin_elementwise_max(h2, (v2f)(0.f)) * w2j;
        z[3] += __builtin_elementwise_max(h3, (v2f)(0.f)) * w2j;
    }

#pragma unroll
    for (int i = 0; i < 4; i++) {
        int e = e0 + i * 256;
        if (e < NEDGES) {
            float ga = 1.f / (1.f + expf(-z[i].x));
            float gb = 1.f / (1.f + expf(-z[i].y));
            g1[e] = ga; g2[e] = gb;
            int c = ei[NEDGES + e];
            atomicAdd(&deg1[c], ga);
            atomicAdd(&deg2[c], gb);
            atomicAdd(&cnt[c], 1);
        }
    }
}

// ---------------- deg -> rsqrt(deg) in place (deg >= 1 always)
__global__ void k_rsqrt(float* __restrict__ d1, float* __restrict__ d2) {
    int i = blockIdx.x * blockDim.x + threadIdx.x;
    if (i < NNODES) { d1[i] = rsqrtf(d1[i]); d2[i] = rsqrtf(d2[i]); }
}

// ---------------- scan phase 1: per-256-block exclusive scan + block sums
__global__ __launch_bounds__(256) void k_scan1(const int* __restrict__ cnt,
                                               int* __restrict__ offs,
                                               int* __restrict__ partial) {
    __shared__ int s[256];
    int t = threadIdx.x;
    int gid = blockIdx.x * 256 + t;
    int own = (gid < NNODES) ? cnt[gid] : 0;
    s[t] = own;
    __syncthreads();
    for (int off = 1; off < 256; off <<= 1) {
        int v = (t >= off) ? s[t - off] : 0;
        __syncthreads();
        s[t] += v;
        __syncthreads();
    }
    if (gid < NNODES) offs[gid] = s[t] - own;   // exclusive
    if (t == 255) partial[blockIdx.x] = s[255];
}

// ---------------- scan phase 2: single block scans the block sums (exclusive)
__global__ __launch_bounds__(512) void k_scan2(int* __restrict__ partial) {
    __shared__ int s[512];
    int t = threadIdx.x;
    int own = (t < NBLK_SCAN) ? partial[t] : 0;
    s[t] = own;
    __syncthreads();
    for (int off = 1; off < 512; off <<= 1) {
        int v = (t >= off) ? s[t - off] : 0;
        __syncthreads();
        s[t] += v;
        __syncthreads();
    }
    if (t < NBLK_SCAN) partial[t] = s[t] - own;  // exclusive
}

// ---------------- scan phase 3: add block offsets; init cursor; offs[N]=E
__global__ void k_scan3(int* __restrict__ offs, const int* __restrict__ partial,
                        int* __restrict__ cur) {
    int gid = blockIdx.x * blockDim.x + threadIdx.x;
    if (gid < NNODES) {
        int v = offs[gid] + partial[gid >> 8];
        offs[gid] = v;
        cur[gid] = v;
    }
    if (gid == 0) offs[NNODES] = NEDGES;
}

// ---------------- scatter edges into CSR slots + precompute per-layer norms
__global__ __launch_bounds__(256) void k_scatter(
    const int* __restrict__ ei, const float* __restrict__ g1,
    const float* __restrict__ g2, const float* __restrict__ dinv1,
    const float* __restrict__ dinv2, int* __restrict__ cur,
    int* __restrict__ prow, float* __restrict__ wl1, float* __restrict__ wl2) {
    int e = blockIdx.x * 256 + threadIdx.x;
    if (e >= NEDGES) return;
    int r = ei[e], c = ei[NEDGES + e];
    int pos = atomicAdd(&cur[c], 1);
    prow[pos] = r;
    wl1[pos] = dinv1[r] * g1[e] * dinv1[c];
    wl2[pos] = dinv2[r] * g2[e] * dinv2[c];
}

// ---------------- fp32 GEMM: Y[M,128] = act(X)[M,128] @ W[128,128]
template <int RELU>
__global__ __launch_bounds__(256) void k_gemm(const float* __restrict__ X,
                                              const float* __restrict__ W,
                                              float* __restrict__ Y, int M) {
    __shared__ __align__(16) float sX[64 * 68];
    __shared__ __align__(16) float sW[64 * 132];
    int t = threadIdx.x;
    int row0 = blockIdx.x * 64;
    int tx = t & 15, ty = t >> 4;

    float acc[4][8];
#pragma unroll
    for (int i = 0; i < 4; i++)
#pragma unroll
        for (int j = 0; j < 8; j++) acc[i][j] = 0.f;

    for (int kt = 0; kt < 128; kt += 64) {
        for (int i = t; i < 1024; i += 256) {
            int r = i >> 4, c4 = i & 15;
            float4 v = make_float4(0.f, 0.f, 0.f, 0.f);
            if (row0 + r < M) v = ((const float4*)X)[(size_t)(row0 + r) * 32 + (kt >> 2) + c4];
            if (RELU) {
                v.x = fmaxf(v.x, 0.f); v.y = fmaxf(v.y, 0.f);
                v.z = fmaxf(v.z, 0.f); v.w = fmaxf(v.w, 0.f);
            }
            ((float4*)(sX + r * 68))[c4] = v;
        }
        for (int i = t; i < 2048; i += 256) {
            int r = i >> 5, c4 = i & 31;
            float4 v = ((const float4*)W)[(size_t)(kt + r) * 32 + c4];
            ((float4*)(sW + r * 132))[c4] = v;
        }
        __syncthreads();
#pragma unroll 8
        for (int k = 0; k < 64; k++) {
            float xv[4];
#pragma unroll
            for (int i = 0; i < 4; i++) xv[i] = sX[(ty * 4 + i) * 68 + k];
            float4 wA = *(const float4*)(sW + k * 132 + tx * 4);
            float4 wB = *(const float4*)(sW + k * 132 + 64 + tx * 4);
#pragma unroll
            for (int i = 0; i < 4; i++) {
                acc[i][0] += xv[i] * wA.x; acc[i][1] += xv[i] * wA.y;
                acc[i][2] += xv[i] * wA.z; acc[i][3] += xv[i] * wA.w;
                acc[i][4] += xv[i] * wB.x; acc[i][5] += xv[i] * wB.y;
                acc[i][6] += xv[i] * wB.z; acc[i][7] += xv[i] * wB.w;
            }
        }
        __syncthreads();
    }
#pragma unroll
    for (int i = 0; i < 4; i++) {
        int r = row0 + ty * 4 + i;
        if (r < M) {
            float4 o1 = make_float4(acc[i][0], acc[i][1], acc[i][2], acc[i][3]);
            float4 o2 = make_float4(acc[i][4], acc[i][5], acc[i][6], acc[i][7]);
            *(float4*)(Y + (size_t)r * 128 + tx * 4) = o1;
            *(float4*)(Y + (size_t)r * 128 + 64 + tx * 4) = o2;
        }
    }
}

// ---------------- CSR aggregation: one wave per node, register accumulation.
__global__ __launch_bounds__(256) void k_aggcsr(
    const int* __restrict__ offs, const int* __restrict__ prow,
    const float* __restrict__ wl, const float* __restrict__ dinv,
    const float* __restrict__ h, float* __restrict__ out) {
    int node = blockIdx.x * 4 + (threadIdx.x >> 6);
    if (node >= NNODES) return;
    int lane = threadIdx.x & 63;
    int beg = offs[node], end = offs[node + 1];
    float d = dinv[node];
    float2 hv = ((const float2*)h)[(size_t)node * 64 + lane];
    float2 acc;
    acc.x = d * d * hv.x;
    acc.y = d * d * hv.y;
    int   r_n = 0; float w_n = 0.f;
    if (beg < end) { r_n = prow[beg]; w_n = wl[beg]; }
    for (int e = beg; e < end; e++) {
        int   r = r_n;
        float w = w_n;
        if (e + 1 < end) { r_n = prow[e + 1]; w_n = wl[e + 1]; }
        float2 v = ((const float2*)h)[(size_t)r * 64 + lane];
        acc.x += w * v.x;
        acc.y += w * v.y;
    }
    ((float2*)out)[(size_t)node * 64 + lane] = acc;
}

extern "C" void kernel_launch(void* const* d_in, const int* in_sizes, int n_in,
                              void* d_out, int out_size, void* d_ws, size_t ws_size,
                              hipStream_t stream) {
    const float* x    = (const float*)d_in[0];
    const int*   ei   = (const int*)d_in[1];
    const float* ea   = (const float*)d_in[2];
    const float* W1   = (const float*)d_in[3];
    const float* m1w1 = (const float*)d_in[4];
    const float* m1b1 = (const float*)d_in[5];
    const float* m1w2 = (const float*)d_in[6];
    const float* m1b2 = (const float*)d_in[7];
    const float* W2   = (const float*)d_in[8];
    const float* m2w1 = (const float*)d_in[9];
    const float* m2b1 = (const float*)d_in[10];
    const float* m2w2 = (const float*)d_in[11];
    const float* m2b2 = (const float*)d_in[12];
    float* out = (float*)d_out;

    float* ws    = (float*)d_ws;
    float* g1    = ws;                               // E
    float* g2    = g1 + NEDGES;                      // E
    float* deg1  = g2 + NEDGES;                      // N
    float* deg2  = deg1 + NNODES;                    // N
    float* hbuf  = deg2 + NNODES;                    // N*128
    float* aggbf = hbuf + (size_t)NNODES * 128;      // N*128
    float* wint  = aggbf + (size_t)NNODES * 128;     // 4096
    float* bw2   = wint + 4096;                      // 512
    float* wl1   = bw2 + 512;                        // E
    float* wl2   = wl1 + NEDGES;                     // E
    int*   cnt   = (int*)(wl2 + NEDGES);             // N (also cursor)
    int*   offs  = cnt + NNODES;                     // N+1
    int*   part  = offs + NNODES + 1;                // 1024
    int*   prow  = part + 1024;                      // E

    k_prep<<<18, 256, 0, stream>>>(m1w1, m2w1, m1b1, m2b1, m1w2, m2w2, wint, bw2);
    k_deg_init<<<(NNODES + 255) / 256, 256, 0, stream>>>(deg1, deg2, cnt);
    k_gates7<<<(NEDGES + 1023) / 1024, 256, 0, stream>>>(ea, ei, wint, bw2, m1b2, m2b2,
                                                         g1, g2, deg1, deg2, cnt);
    k_rsqrt<<<(NNODES + 255) / 256, 256, 0, stream>>>(deg1, deg2);

    // CSR build (graph shared by both layers)
    k_scan1<<<NBLK_SCAN, 256, 0, stream>>>(cnt, offs, part);
    k_scan2<<<1, 512, 0, stream>>>(part);
    k_scan3<<<(NNODES + 255) / 256, 256, 0, stream>>>(offs, part, cnt);
    k_scatter<<<NEDGES / 256, 256, 0, stream>>>(ei, g1, g2, deg1, deg2,
                                                cnt, prow, wl1, wl2);

    // layer 1
    k_gemm<0><<<(NNODES + 63) / 64, 256, 0, stream>>>(x, W1, hbuf, NNODES);
    k_aggcsr<<<(NNODES + 3) / 4, 256, 0, stream>>>(offs, prow, wl1, deg1, hbuf, aggbf);

    // layer 2 (relu fused into GEMM load)
    k_gemm<1><<<(NNODES + 63) / 64, 256, 0, stream>>>(aggbf, W2, hbuf, NNODES);
    k_aggcsr<<<(NNODES + 3) / 4, 256, 0, stream>>>(offs, prow, wl2, deg2, hbuf, out);
}

// Round 5
// 955.263 us; speedup vs baseline: 1.0290x; 1.0290x over previous
//
#include <hip/hip_runtime.h>
#include <math.h>

#define NNODES 100000
#define NEDGES 1600000
#define DF 128
#define ED 16
#define NBLK_SCAN ((NNODES + 255) / 256)   // 391

typedef float v2f __attribute__((ext_vector_type(2)));

// ---------------- prep: interleave layer1/layer2 edge-MLP params for packed math
// wint[j*32 + 2k + L] = wL[k*128 + j]   (j in [0,128), k in [0,16), L in {0,1})
// bw2[2j + L] = bL[j] ;  bw2[256 + 2j + L] = w2L[j]
__global__ void k_prep(const float* __restrict__ m1w1, const float* __restrict__ m2w1,
                       const float* __restrict__ m1b1, const float* __restrict__ m2b1,
                       const float* __restrict__ m1w2, const float* __restrict__ m2w2,
                       float* __restrict__ wint, float* __restrict__ bw2) {
    int t = blockIdx.x * blockDim.x + threadIdx.x;
    if (t < 4096) {
        int j = t >> 5, r = t & 31;
        int k = r >> 1, L = r & 1;
        const float* src = L ? m2w1 : m1w1;
        wint[t] = src[k * DF + j];
    } else if (t < 4096 + 256) {
        int i = t - 4096;
        int j = i >> 1, L = i & 1;
        bw2[i] = L ? m2b1[j] : m1b1[j];
    } else if (t < 4096 + 512) {
        int i = t - 4096 - 256;
        int j = i >> 1, L = i & 1;
        bw2[256 + i] = L ? m2w2[j] : m1w2[j];
    }
}

// ---------------- deg init (self-loop weight 1) + zero in-degree counters
__global__ void k_deg_init(float* __restrict__ d1, float* __restrict__ d2,
                           int* __restrict__ cnt) {
    int i = blockIdx.x * blockDim.x + threadIdx.x;
    if (i < NNODES) { d1[i] = 1.f; d2[i] = 1.f; cnt[i] = 0; }
}

// ---------------- edge gates, BOTH layers packed into v_pk_fma_f32 halves.
// v8: measured cost model across R0/R3/R4:
//   ds_read_b64 uniform broadcast = 2.78 cyc (R0 fit: 263us), b128 = ~13 cyc
//   (R3 fit: 306us), and occupancy (TLP) is the latency-hiding engine -- the
//   VGPR cliff at 64 halves waves/SIMD (R4: 84 VGPR -> 25% occ -> 318us).
// Therefore: TWO edges per thread (a[2][16]=32 regs keeps total ~55 VGPR,
// same occupancy class as R0's 36), b64 weight reads, unroll-2 j pipelining.
// Per-edge LDS insts 36 -> 18: LDS pipe ~130us, VALU ~124us, both balanced.
__global__ __launch_bounds__(256) void k_gates8(
    const float* __restrict__ ea, const int* __restrict__ ei,
    const float* __restrict__ wint, const float* __restrict__ bw2,
    const float* __restrict__ b21, const float* __restrict__ b22,
    float* __restrict__ g1, float* __restrict__ g2,
    float* __restrict__ deg1, float* __restrict__ deg2,
    int* __restrict__ cnt) {
    __shared__ __align__(16) v2f sw[2048];          // 16 KB interleaved weights
    __shared__ __align__(16) v2f sb[128], s2[128];  // bias pairs, w2 pairs
    int t = threadIdx.x;
    for (int i = t; i < 2048; i += 256) sw[i] = ((const v2f*)wint)[i];
    if (t < 128) { sb[t] = ((const v2f*)bw2)[t]; s2[t] = ((const v2f*)(bw2 + 256))[t]; }
    __syncthreads();

    int e0 = blockIdx.x * 512 + t;   // edges e0 and e0+256 (E = 3125*512, no tail)

    float a0[16], a1[16];
    {
        const float4* p0 = (const float4*)(ea + (size_t)e0 * ED);
        const float4* p1 = (const float4*)(ea + (size_t)(e0 + 256) * ED);
#pragma unroll
        for (int q = 0; q < 4; q++) {
            float4 v = p0[q];
            a0[q*4+0] = v.x; a0[q*4+1] = v.y; a0[q*4+2] = v.z; a0[q*4+3] = v.w;
            float4 w = p1[q];
            a1[q*4+0] = w.x; a1[q*4+1] = w.y; a1[q*4+2] = w.z; a1[q*4+3] = w.w;
        }
    }

    v2f z0, z1;
    z0.x = b21[0]; z0.y = b22[0];
    z1 = z0;

#pragma unroll 2
    for (int j = 0; j < 128; j++) {
        const v2f* wp = sw + j * 16;   // 16 x ds_read_b64, uniform broadcast
        v2f h0 = sb[j];
        v2f h1 = h0;
#pragma unroll
        for (int k = 0; k < 16; k++) {
            v2f q = wp[k];
            h0 += q * a0[k];    // v_pk_fma_f32
            h1 += q * a1[k];
        }
        v2f w2j = s2[j];
        z0 += __builtin_elementwise_max(h0, (v2f)(0.f)) * w2j;
        z1 += __builtin_elementwise_max(h1, (v2f)(0.f)) * w2j;
    }

    {
        float ga = 1.f / (1.f + expf(-z0.x));
        float gb = 1.f / (1.f + expf(-z0.y));
        g1[e0] = ga; g2[e0] = gb;
        int c = ei[NEDGES + e0];
        atomicAdd(&deg1[c], ga);
        atomicAdd(&deg2[c], gb);
        atomicAdd(&cnt[c], 1);
    }
    {
        int e1 = e0 + 256;
        float ga = 1.f / (1.f + expf(-z1.x));
        float gb = 1.f / (1.f + expf(-z1.y));
        g1[e1] = ga; g2[e1] = gb;
        int c = ei[NEDGES + e1];
        atomicAdd(&deg1[c], ga);
        atomicAdd(&deg2[c], gb);
        atomicAdd(&cnt[c], 1);
    }
}

// ---------------- deg -> rsqrt(deg) in place (deg >= 1 always)
__global__ void k_rsqrt(float* __restrict__ d1, float* __restrict__ d2) {
    int i = blockIdx.x * blockDim.x + threadIdx.x;
    if (i < NNODES) { d1[i] = rsqrtf(d1[i]); d2[i] = rsqrtf(d2[i]); }
}

// ---------------- scan phase 1: per-256-block exclusive scan + block sums
__global__ __launch_bounds__(256) void k_scan1(const int* __restrict__ cnt,
                                               int* __restrict__ offs,
                                               int* __restrict__ partial) {
    __shared__ int s[256];
    int t = threadIdx.x;
    int gid = blockIdx.x * 256 + t;
    int own = (gid < NNODES) ? cnt[gid] : 0;
    s[t] = own;
    __syncthreads();
    for (int off = 1; off < 256; off <<= 1) {
        int v = (t >= off) ? s[t - off] : 0;
        __syncthreads();
        s[t] += v;
        __syncthreads();
    }
    if (gid < NNODES) offs[gid] = s[t] - own;   // exclusive
    if (t == 255) partial[blockIdx.x] = s[255];
}

// ---------------- scan phase 2: single block scans the block sums (exclusive)
__global__ __launch_bounds__(512) void k_scan2(int* __restrict__ partial) {
    __shared__ int s[512];
    int t = threadIdx.x;
    int own = (t < NBLK_SCAN) ? partial[t] : 0;
    s[t] = own;
    __syncthreads();
    for (int off = 1; off < 512; off <<= 1) {
        int v = (t >= off) ? s[t - off] : 0;
        __syncthreads();
        s[t] += v;
        __syncthreads();
    }
    if (t < NBLK_SCAN) partial[t] = s[t] - own;  // exclusive
}

// ---------------- scan phase 3: add block offsets; init cursor; offs[N]=E
__global__ void k_scan3(int* __restrict__ offs, const int* __restrict__ partial,
                        int* __restrict__ cur) {
    int gid = blockIdx.x * blockDim.x + threadIdx.x;
    if (gid < NNODES) {
        int v = offs[gid] + partial[gid >> 8];
        offs[gid] = v;
        cur[gid] = v;
    }
    if (gid == 0) offs[NNODES] = NEDGES;
}

// ---------------- scatter edges into CSR slots + precompute per-layer norms
__global__ __launch_bounds__(256) void k_scatter(
    const int* __restrict__ ei, const float* __restrict__ g1,
    const float* __restrict__ g2, const float* __restrict__ dinv1,
    const float* __restrict__ dinv2, int* __restrict__ cur,
    int* __restrict__ prow, float* __restrict__ wl1, float* __restrict__ wl2) {
    int e = blockIdx.x * 256 + threadIdx.x;
    if (e >= NEDGES) return;
    int r = ei[e], c = ei[NEDGES + e];
    int pos = atomicAdd(&cur[c], 1);
    prow[pos] = r;
    wl1[pos] = dinv1[r] * g1[e] * dinv1[c];
    wl2[pos] = dinv2[r] * g2[e] * dinv2[c];
}

// ---------------- fp32 GEMM: Y[M,128] = act(X)[M,128] @ W[128,128]
template <int RELU>
__global__ __launch_bounds__(256) void k_gemm(const float* __restrict__ X,
                                              const float* __restrict__ W,
                                              float* __restrict__ Y, int M) {
    __shared__ __align__(16) float sX[64 * 68];
    __shared__ __align__(16) float sW[64 * 132];
    int t = threadIdx.x;
    int row0 = blockIdx.x * 64;
    int tx = t & 15, ty = t >> 4;

    float acc[4][8];
#pragma unroll
    for (int i = 0; i < 4; i++)
#pragma unroll
        for (int j = 0; j < 8; j++) acc[i][j] = 0.f;

    for (int kt = 0; kt < 128; kt += 64) {
        for (int i = t; i < 1024; i += 256) {
            int r = i >> 4, c4 = i & 15;
            float4 v = make_float4(0.f, 0.f, 0.f, 0.f);
            if (row0 + r < M) v = ((const float4*)X)[(size_t)(row0 + r) * 32 + (kt >> 2) + c4];
            if (RELU) {
                v.x = fmaxf(v.x, 0.f); v.y = fmaxf(v.y, 0.f);
                v.z = fmaxf(v.z, 0.f); v.w = fmaxf(v.w, 0.f);
            }
            ((float4*)(sX + r * 68))[c4] = v;
        }
        for (int i = t; i < 2048; i += 256) {
            int r = i >> 5, c4 = i & 31;
            float4 v = ((const float4*)W)[(size_t)(kt + r) * 32 + c4];
            ((float4*)(sW + r * 132))[c4] = v;
        }
        __syncthreads();
#pragma unroll 8
        for (int k = 0; k < 64; k++) {
            float xv[4];
#pragma unroll
            for (int i = 0; i < 4; i++) xv[i] = sX[(ty * 4 + i) * 68 + k];
            float4 wA = *(const float4*)(sW + k * 132 + tx * 4);
            float4 wB = *(const float4*)(sW + k * 132 + 64 + tx * 4);
#pragma unroll
            for (int i = 0; i < 4; i++) {
                acc[i][0] += xv[i] * wA.x; acc[i][1] += xv[i] * wA.y;
                acc[i][2] += xv[i] * wA.z; acc[i][3] += xv[i] * wA.w;
                acc[i][4] += xv[i] * wB.x; acc[i][5] += xv[i] * wB.y;
                acc[i][6] += xv[i] * wB.z; acc[i][7] += xv[i] * wB.w;
            }
        }
        __syncthreads();
    }
#pragma unroll
    for (int i = 0; i < 4; i++) {
        int r = row0 + ty * 4 + i;
        if (r < M) {
            float4 o1 = make_float4(acc[i][0], acc[i][1], acc[i][2], acc[i][3]);
            float4 o2 = make_float4(acc[i][4], acc[i][5], acc[i][6], acc[i][7]);
            *(float4*)(Y + (size_t)r * 128 + tx * 4) = o1;
            *(float4*)(Y + (size_t)r * 128 + 64 + tx * 4) = o2;
        }
    }
}

// ---------------- CSR aggregation: one wave per node, register accumulation.
__global__ __launch_bounds__(256) void k_aggcsr(
    const int* __restrict__ offs, const int* __restrict__ prow,
    const float* __restrict__ wl, const float* __restrict__ dinv,
    const float* __restrict__ h, float* __restrict__ out) {
    int node = blockIdx.x * 4 + (threadIdx.x >> 6);
    if (node >= NNODES) return;
    int lane = threadIdx.x & 63;
    int beg = offs[node], end = offs[node + 1];
    float d = dinv[node];
    float2 hv = ((const float2*)h)[(size_t)node * 64 + lane];
    float2 acc;
    acc.x = d * d * hv.x;
    acc.y = d * d * hv.y;
    int   r_n = 0; float w_n = 0.f;
    if (beg < end) { r_n = prow[beg]; w_n = wl[beg]; }
    for (int e = beg; e < end; e++) {
        int   r = r_n;
        float w = w_n;
        if (e + 1 < end) { r_n = prow[e + 1]; w_n = wl[e + 1]; }
        float2 v = ((const float2*)h)[(size_t)r * 64 + lane];
        acc.x += w * v.x;
        acc.y += w * v.y;
    }
    ((float2*)out)[(size_t)node * 64 + lane] = acc;
}

extern "C" void kernel_launch(void* const* d_in, const int* in_sizes, int n_in,
                              void* d_out, int out_size, void* d_ws, size_t ws_size,
                              hipStream_t stream) {
    const float* x    = (const float*)d_in[0];
    const int*   ei   = (const int*)d_in[1];
    const float* ea   = (const float*)d_in[2];
    const float* W1   = (const float*)d_in[3];
    const float* m1w1 = (const float*)d_in[4];
    const float* m1b1 = (const float*)d_in[5];
    const float* m1w2 = (const float*)d_in[6];
    const float* m1b2 = (const float*)d_in[7];
    const float* W2   = (const float*)d_in[8];
    const float* m2w1 = (const float*)d_in[9];
    const float* m2b1 = (const float*)d_in[10];
    const float* m2w2 = (const float*)d_in[11];
    const float* m2b2 = (const float*)d_in[12];
    float* out = (float*)d_out;

    float* ws    = (float*)d_ws;
    float* g1    = ws;                               // E
    float* g2    = g1 + NEDGES;                      // E
    float* deg1  = g2 + NEDGES;                      // N
    float* deg2  = deg1 + NNODES;                    // N
    float* hbuf  = deg2 + NNODES;                    // N*128
    float* aggbf = hbuf + (size_t)NNODES * 128;      // N*128
    float* wint  = aggbf + (size_t)NNODES * 128;     // 4096
    float* bw2   = wint + 4096;                      // 512
    float* wl1   = bw2 + 512;                        // E
    float* wl2   = wl1 + NEDGES;                     // E
    int*   cnt   = (int*)(wl2 + NEDGES);             // N (also cursor)
    int*   offs  = cnt + NNODES;                     // N+1
    int*   part  = offs + NNODES + 1;                // 1024
    int*   prow  = part + 1024;                      // E

    k_prep<<<18, 256, 0, stream>>>(m1w1, m2w1, m1b1, m2b1, m1w2, m2w2, wint, bw2);
    k_deg_init<<<(NNODES + 255) / 256, 256, 0, stream>>>(deg1, deg2, cnt);
    k_gates8<<<NEDGES / 512, 256, 0, stream>>>(ea, ei, wint, bw2, m1b2, m2b2,
                                               g1, g2, deg1, deg2, cnt);
    k_rsqrt<<<(NNODES + 255) / 256, 256, 0, stream>>>(deg1, deg2);

    // CSR build (graph shared by both layers)
    k_scan1<<<NBLK_SCAN, 256, 0, stream>>>(cnt, offs, part);
    k_scan2<<<1, 512, 0, stream>>>(part);
    k_scan3<<<(NNODES + 255) / 256, 256, 0, stream>>>(offs, part, cnt);
    k_scatter<<<NEDGES / 256, 256, 0, stream>>>(ei, g1, g2, deg1, deg2,
                                                cnt, prow, wl1, wl2);

    // layer 1
    k_gemm<0><<<(NNODES + 63) / 64, 256, 0, stream>>>(x, W1, hbuf, NNODES);
    k_aggcsr<<<(NNODES + 3) / 4, 256, 0, stream>>>(offs, prow, wl1, deg1, hbuf, aggbf);

    // layer 2 (relu fused into GEMM load)
    k_gemm<1><<<(NNODES + 63) / 64, 256, 0, stream>>>(aggbf, W2, hbuf, NNODES);
    k_aggcsr<<<(NNODES + 3) / 4, 256, 0, stream>>>(offs, prow, wl2, deg2, hbuf, out);
}

// Round 7
// 909.399 us; speedup vs baseline: 1.0808x; 1.0504x over previous
//
#include <hip/hip_runtime.h>
#include <math.h>

#define NNODES 100000
#define NEDGES 1600000
#define DF 128
#define ED 16
#define NBLK_SCAN ((NNODES + 255) / 256)   // 391

typedef float v2f __attribute__((ext_vector_type(2)));

// ---------------- prep: interleave layer1/layer2 edge-MLP params for packed math
// wint[j*32 + 2k + L] = wL[k*128 + j]   (j in [0,128), k in [0,16), L in {0,1})
// bw2[2j + L] = bL[j] ;  bw2[256 + 2j + L] = w2L[j]
__global__ void k_prep(const float* __restrict__ m1w1, const float* __restrict__ m2w1,
                       const float* __restrict__ m1b1, const float* __restrict__ m2b1,
                       const float* __restrict__ m1w2, const float* __restrict__ m2w2,
                       float* __restrict__ wint, float* __restrict__ bw2) {
    int t = blockIdx.x * blockDim.x + threadIdx.x;
    if (t < 4096) {
        int j = t >> 5, r = t & 31;
        int k = r >> 1, L = r & 1;
        const float* src = L ? m2w1 : m1w1;
        wint[t] = src[k * DF + j];
    } else if (t < 4096 + 256) {
        int i = t - 4096;
        int j = i >> 1, L = i & 1;
        bw2[i] = L ? m2b1[j] : m1b1[j];
    } else if (t < 4096 + 512) {
        int i = t - 4096 - 256;
        int j = i >> 1, L = i & 1;
        bw2[256 + i] = L ? m2w2[j] : m1w2[j];
    }
}

// ---------------- deg init (self-loop weight 1) + zero in-degree counters
__global__ void k_deg_init(float* __restrict__ d1, float* __restrict__ d2,
                           int* __restrict__ cnt) {
    int i = blockIdx.x * blockDim.x + threadIdx.x;
    if (i < NNODES) { d1[i] = 1.f; d2[i] = 1.f; cnt[i] = 0; }
}

// ---------------- edge gates, BOTH layers packed into v_pk_fma_f32 halves.
// v9 (re-run; R6 bench died to a workspace-overflow suspect, not this kernel):
// cross-round fit (R0/R3/R4/R5): eff cyc per uniform LDS broadcast =
// ~120cyc latency / resident waves (R0 21.8 waves -> 2.78cyc; R5 14.4 -> 6.5;
// R4 8 -> 13.6). The kernel is LDS-LATENCY bound; residency is the lever, and
// every multi-edge-per-thread variant lost residency (longer blocks + cohort
// quantization). So: R0's exact per-thread structure (1 edge, b64 broadcasts,
// ~36 VGPR) in 512-THREAD blocks -- full 32-wave/CU residency needs only 4
// blocks/CU (robust), instead of 8 with 256-thread blocks.
__global__ __launch_bounds__(512) void k_gates9(
    const float* __restrict__ ea, const int* __restrict__ ei,
    const float* __restrict__ wint, const float* __restrict__ bw2,
    const float* __restrict__ b21, const float* __restrict__ b22,
    float* __restrict__ g1, float* __restrict__ g2,
    float* __restrict__ deg1, float* __restrict__ deg2,
    int* __restrict__ cnt) {
    __shared__ __align__(16) v2f sw[2048];          // 16 KB interleaved weights
    __shared__ __align__(16) v2f sb[128], s2[128];  // bias pairs, w2 pairs
    int t = threadIdx.x;
    for (int i = t; i < 2048; i += 512) sw[i] = ((const v2f*)wint)[i];
    if (t < 128) { sb[t] = ((const v2f*)bw2)[t]; s2[t] = ((const v2f*)(bw2 + 256))[t]; }
    __syncthreads();

    int e = blockIdx.x * 512 + t;   // E = 3125*512 exactly, no tail
    if (e >= NEDGES) return;

    float a[16];
    const float4* ea4 = (const float4*)(ea + (size_t)e * ED);
#pragma unroll
    for (int q = 0; q < 4; q++) {
        float4 v = ea4[q];
        a[q*4+0] = v.x; a[q*4+1] = v.y; a[q*4+2] = v.z; a[q*4+3] = v.w;
    }

    v2f z;
    z.x = b21[0]; z.y = b22[0];
#pragma unroll 2
    for (int j = 0; j < 128; j++) {
        const v2f* wp = sw + j * 16;
        v2f h = sb[j];
#pragma unroll
        for (int k = 0; k < 16; k++) h += wp[k] * a[k];   // v_pk_fma_f32
        v2f hr = __builtin_elementwise_max(h, (v2f)(0.f)); // v_pk_max_f32
        z += hr * s2[j];                                   // v_pk_fma_f32
    }
    float ga = 1.f / (1.f + expf(-z.x));
    float gb = 1.f / (1.f + expf(-z.y));
    g1[e] = ga; g2[e] = gb;
    int c = ei[NEDGES + e];
    atomicAdd(&deg1[c], ga);
    atomicAdd(&deg2[c], gb);
    atomicAdd(&cnt[c], 1);
}

// ---------------- deg -> rsqrt(deg) in place (deg >= 1 always)
__global__ void k_rsqrt(float* __restrict__ d1, float* __restrict__ d2) {
    int i = blockIdx.x * blockDim.x + threadIdx.x;
    if (i < NNODES) { d1[i] = rsqrtf(d1[i]); d2[i] = rsqrtf(d2[i]); }
}

// ---------------- scan phase 1: per-256-block exclusive scan + block sums
__global__ __launch_bounds__(256) void k_scan1(const int* __restrict__ cnt,
                                               int* __restrict__ offs,
                                               int* __restrict__ partial) {
    __shared__ int s[256];
    int t = threadIdx.x;
    int gid = blockIdx.x * 256 + t;
    int own = (gid < NNODES) ? cnt[gid] : 0;
    s[t] = own;
    __syncthreads();
    for (int off = 1; off < 256; off <<= 1) {
        int v = (t >= off) ? s[t - off] : 0;
        __syncthreads();
        s[t] += v;
        __syncthreads();
    }
    if (gid < NNODES) offs[gid] = s[t] - own;   // exclusive
    if (t == 255) partial[blockIdx.x] = s[255];
}

// ---------------- scan phase 2: single block scans the block sums (exclusive)
__global__ __launch_bounds__(512) void k_scan2(int* __restrict__ partial) {
    __shared__ int s[512];
    int t = threadIdx.x;
    int own = (t < NBLK_SCAN) ? partial[t] : 0;
    s[t] = own;
    __syncthreads();
    for (int off = 1; off < 512; off <<= 1) {
        int v = (t >= off) ? s[t - off] : 0;
        __syncthreads();
        s[t] += v;
        __syncthreads();
    }
    if (t < NBLK_SCAN) partial[t] = s[t] - own;  // exclusive
}

// ---------------- scan phase 3: add block offsets; init cursor; offs[N]=E
__global__ void k_scan3(int* __restrict__ offs, const int* __restrict__ partial,
                        int* __restrict__ cur) {
    int gid = blockIdx.x * blockDim.x + threadIdx.x;
    if (gid < NNODES) {
        int v = offs[gid] + partial[gid >> 8];
        offs[gid] = v;
        cur[gid] = v;
    }
    if (gid == 0) offs[NNODES] = NEDGES;
}

// ---------------- scatter edges into CSR slots; per-edge weights for BOTH
// layers packed in one float2 (8-B store) -- 2 random stores instead of 3,
// and aggcsr gets both layer weights in one 8-B line. Footprint identical to
// the rounds-0..5 layout (wl1+wl2 == wl12).
__global__ __launch_bounds__(256) void k_scatter(
    const int* __restrict__ ei, const float* __restrict__ g1,
    const float* __restrict__ g2, const float* __restrict__ dinv1,
    const float* __restrict__ dinv2, int* __restrict__ cur,
    int* __restrict__ prow, float2* __restrict__ wl12) {
    int e = blockIdx.x * 256 + threadIdx.x;
    if (e >= NEDGES) return;
    int r = ei[e], c = ei[NEDGES + e];
    int pos = atomicAdd(&cur[c], 1);
    prow[pos] = r;
    float2 w;
    w.x = dinv1[r] * g1[e] * dinv1[c];
    w.y = dinv2[r] * g2[e] * dinv2[c];
    wl12[pos] = w;
}

// ---------------- fp32 GEMM: Y[M,128] = act(X)[M,128] @ W[128,128]
template <int RELU>
__global__ __launch_bounds__(256) void k_gemm(const float* __restrict__ X,
                                              const float* __restrict__ W,
                                              float* __restrict__ Y, int M) {
    __shared__ __align__(16) float sX[64 * 68];
    __shared__ __align__(16) float sW[64 * 132];
    int t = threadIdx.x;
    int row0 = blockIdx.x * 64;
    int tx = t & 15, ty = t >> 4;

    float acc[4][8];
#pragma unroll
    for (int i = 0; i < 4; i++)
#pragma unroll
        for (int j = 0; j < 8; j++) acc[i][j] = 0.f;

    for (int kt = 0; kt < 128; kt += 64) {
        for (int i = t; i < 1024; i += 256) {
            int r = i >> 4, c4 = i & 15;
            float4 v = make_float4(0.f, 0.f, 0.f, 0.f);
            if (row0 + r < M) v = ((const float4*)X)[(size_t)(row0 + r) * 32 + (kt >> 2) + c4];
            if (RELU) {
                v.x = fmaxf(v.x, 0.f); v.y = fmaxf(v.y, 0.f);
                v.z = fmaxf(v.z, 0.f); v.w = fmaxf(v.w, 0.f);
            }
            ((float4*)(sX + r * 68))[c4] = v;
        }
        for (int i = t; i < 2048; i += 256) {
            int r = i >> 5, c4 = i & 31;
            float4 v = ((const float4*)W)[(size_t)(kt + r) * 32 + c4];
            ((float4*)(sW + r * 132))[c4] = v;
        }
        __syncthreads();
#pragma unroll 8
        for (int k = 0; k < 64; k++) {
            float xv[4];
#pragma unroll
            for (int i = 0; i < 4; i++) xv[i] = sX[(ty * 4 + i) * 68 + k];
            float4 wA = *(const float4*)(sW + k * 132 + tx * 4);
            float4 wB = *(const float4*)(sW + k * 132 + 64 + tx * 4);
#pragma unroll
            for (int i = 0; i < 4; i++) {
                acc[i][0] += xv[i] * wA.x; acc[i][1] += xv[i] * wA.y;
                acc[i][2] += xv[i] * wA.z; acc[i][3] += xv[i] * wA.w;
                acc[i][4] += xv[i] * wB.x; acc[i][5] += xv[i] * wB.y;
                acc[i][6] += xv[i] * wB.z; acc[i][7] += xv[i] * wB.w;
            }
        }
        __syncthreads();
    }
#pragma unroll
    for (int i = 0; i < 4; i++) {
        int r = row0 + ty * 4 + i;
        if (r < M) {
            float4 o1 = make_float4(acc[i][0], acc[i][1], acc[i][2], acc[i][3]);
            float4 o2 = make_float4(acc[i][4], acc[i][5], acc[i][6], acc[i][7]);
            *(float4*)(Y + (size_t)r * 128 + tx * 4) = o1;
            *(float4*)(Y + (size_t)r * 128 + 64 + tx * 4) = o2;
        }
    }
}

// ---------------- CSR aggregation: one wave per node, register accumulation.
// LAYER picks .x/.y from the packed per-edge weight pair.
template <int LAYER>
__global__ __launch_bounds__(256) void k_aggcsr(
    const int* __restrict__ offs, const int* __restrict__ prow,
    const float2* __restrict__ wl12, const float* __restrict__ dinv,
    const float* __restrict__ h, float* __restrict__ out) {
    int node = blockIdx.x * 4 + (threadIdx.x >> 6);
    if (node >= NNODES) return;
    int lane = threadIdx.x & 63;
    int beg = offs[node], end = offs[node + 1];
    float d = dinv[node];
    float2 hv = ((const float2*)h)[(size_t)node * 64 + lane];
    float2 acc;
    acc.x = d * d * hv.x;
    acc.y = d * d * hv.y;
    int    r_n = 0;
    float2 w_n = make_float2(0.f, 0.f);
    if (beg < end) { r_n = prow[beg]; w_n = wl12[beg]; }
    for (int e = beg; e < end; e++) {
        int    r = r_n;
        float2 wp = w_n;
        if (e + 1 < end) { r_n = prow[e + 1]; w_n = wl12[e + 1]; }
        float w = (LAYER == 1) ? wp.x : wp.y;
        float2 v = ((const float2*)h)[(size_t)r * 64 + lane];
        acc.x += w * v.x;
        acc.y += w * v.y;
    }
    ((float2*)out)[(size_t)node * 64 + lane] = acc;
}

extern "C" void kernel_launch(void* const* d_in, const int* in_sizes, int n_in,
                              void* d_out, int out_size, void* d_ws, size_t ws_size,
                              hipStream_t stream) {
    const float* x    = (const float*)d_in[0];
    const int*   ei   = (const int*)d_in[1];
    const float* ea   = (const float*)d_in[2];
    const float* W1   = (const float*)d_in[3];
    const float* m1w1 = (const float*)d_in[4];
    const float* m1b1 = (const float*)d_in[5];
    const float* m1w2 = (const float*)d_in[6];
    const float* m1b2 = (const float*)d_in[7];
    const float* W2   = (const float*)d_in[8];
    const float* m2w1 = (const float*)d_in[9];
    const float* m2b1 = (const float*)d_in[10];
    const float* m2w2 = (const float*)d_in[11];
    const float* m2b2 = (const float*)d_in[12];
    float* out = (float*)d_out;

    // Workspace layout: byte-identical footprint to the rounds-0..5 layout
    // (wl12 occupies the old wl1+wl2 slots).
    float* ws    = (float*)d_ws;
    float* g1    = ws;                               // E
    float* g2    = g1 + NEDGES;                      // E
    float* deg1  = g2 + NEDGES;                      // N
    float* deg2  = deg1 + NNODES;                    // N
    float* hbuf  = deg2 + NNODES;                    // N*128
    float* aggbf = hbuf + (size_t)NNODES * 128;      // N*128
    float* wint  = aggbf + (size_t)NNODES * 128;     // 4096
    float* bw2   = wint + 4096;                      // 512
    float2* wl12 = (float2*)(bw2 + 512);             // E float2 (== old wl1+wl2)
    int*   cnt   = (int*)(wl12 + NEDGES);            // N (also cursor)
    int*   offs  = cnt + NNODES;                     // N+1
    int*   part  = offs + NNODES + 1;                // 1024
    int*   prow  = part + 1024;                      // E

    k_prep<<<18, 256, 0, stream>>>(m1w1, m2w1, m1b1, m2b1, m1w2, m2w2, wint, bw2);
    k_deg_init<<<(NNODES + 255) / 256, 256, 0, stream>>>(deg1, deg2, cnt);
    k_gates9<<<NEDGES / 512, 512, 0, stream>>>(ea, ei, wint, bw2, m1b2, m2b2,
                                               g1, g2, deg1, deg2, cnt);
    k_rsqrt<<<(NNODES + 255) / 256, 256, 0, stream>>>(deg1, deg2);

    // CSR build (graph shared by both layers)
    k_scan1<<<NBLK_SCAN, 256, 0, stream>>>(cnt, offs, part);
    k_scan2<<<1, 512, 0, stream>>>(part);
    k_scan3<<<(NNODES + 255) / 256, 256, 0, stream>>>(offs, part, cnt);
    k_scatter<<<NEDGES / 256, 256, 0, stream>>>(ei, g1, g2, deg1, deg2,
                                                cnt, prow, wl12);

    // layer 1
    k_gemm<0><<<(NNODES + 63) / 64, 256, 0, stream>>>(x, W1, hbuf, NNODES);
    k_aggcsr<1><<<(NNODES + 3) / 4, 256, 0, stream>>>(offs, prow, wl12, deg1, hbuf, aggbf);

    // layer 2 (relu fused into GEMM load)
    k_gemm<1><<<(NNODES + 63) / 64, 256, 0, stream>>>(aggbf, W2, hbuf, NNODES);
    k_aggcsr<2><<<(NNODES + 3) / 4, 256, 0, stream>>>(offs, prow, wl12, deg2, hbuf, out);
}

// Round 8
// 885.689 us; speedup vs baseline: 1.1098x; 1.0268x over previous
//
#include <hip/hip_runtime.h>
#include <math.h>

#define NNODES 100000
#define NEDGES 1600000
#define DF 128
#define ED 16
#define NBLK_SCAN ((NNODES + 255) / 256)   // 391

typedef float v2f __attribute__((ext_vector_type(2)));

// ---------------- prep: interleave layer1/layer2 edge-MLP params for packed math
// wint[j*32 + 2k + L] = wL[k*128 + j]   (j in [0,128), k in [0,16), L in {0,1})
// bw2[2j + L] = bL[j] ;  bw2[256 + 2j + L] = w2L[j]
__global__ void k_prep(const float* __restrict__ m1w1, const float* __restrict__ m2w1,
                       const float* __restrict__ m1b1, const float* __restrict__ m2b1,
                       const float* __restrict__ m1w2, const float* __restrict__ m2w2,
                       float* __restrict__ wint, float* __restrict__ bw2) {
    int t = blockIdx.x * blockDim.x + threadIdx.x;
    if (t < 4096) {
        int j = t >> 5, r = t & 31;
        int k = r >> 1, L = r & 1;
        const float* src = L ? m2w1 : m1w1;
        wint[t] = src[k * DF + j];
    } else if (t < 4096 + 256) {
        int i = t - 4096;
        int j = i >> 1, L = i & 1;
        bw2[i] = L ? m2b1[j] : m1b1[j];
    } else if (t < 4096 + 512) {
        int i = t - 4096 - 256;
        int j = i >> 1, L = i & 1;
        bw2[256 + i] = L ? m2w2[j] : m1w2[j];
    }
}

// ---------------- deg init (self-loop weight 1) + zero in-degree counters
__global__ void k_deg_init(float* __restrict__ d1, float* __restrict__ d2,
                           int* __restrict__ cnt) {
    int i = blockIdx.x * blockDim.x + threadIdx.x;
    if (i < NNODES) { d1[i] = 1.f; d2[i] = 1.f; cnt[i] = 0; }
}

// ---------------- edge gates, BOTH layers packed into v_pk_fma_f32 halves.
// v9: at its structural floor (~262us) -- R0/R5/R7 established the LDS
// broadcast pipe + VALU overlap limit; residency, inst-count and width
// variants all land >= 262. Do not touch.
__global__ __launch_bounds__(512) void k_gates9(
    const float* __restrict__ ea, const int* __restrict__ ei,
    const float* __restrict__ wint, const float* __restrict__ bw2,
    const float* __restrict__ b21, const float* __restrict__ b22,
    float* __restrict__ g1, float* __restrict__ g2,
    float* __restrict__ deg1, float* __restrict__ deg2,
    int* __restrict__ cnt) {
    __shared__ __align__(16) v2f sw[2048];          // 16 KB interleaved weights
    __shared__ __align__(16) v2f sb[128], s2[128];  // bias pairs, w2 pairs
    int t = threadIdx.x;
    for (int i = t; i < 2048; i += 512) sw[i] = ((const v2f*)wint)[i];
    if (t < 128) { sb[t] = ((const v2f*)bw2)[t]; s2[t] = ((const v2f*)(bw2 + 256))[t]; }
    __syncthreads();

    int e = blockIdx.x * 512 + t;   // E = 3125*512 exactly, no tail
    if (e >= NEDGES) return;

    float a[16];
    const float4* ea4 = (const float4*)(ea + (size_t)e * ED);
#pragma unroll
    for (int q = 0; q < 4; q++) {
        float4 v = ea4[q];
        a[q*4+0] = v.x; a[q*4+1] = v.y; a[q*4+2] = v.z; a[q*4+3] = v.w;
    }

    v2f z;
    z.x = b21[0]; z.y = b22[0];
#pragma unroll 2
    for (int j = 0; j < 128; j++) {
        const v2f* wp = sw + j * 16;
        v2f h = sb[j];
#pragma unroll
        for (int k = 0; k < 16; k++) h += wp[k] * a[k];   // v_pk_fma_f32
        v2f hr = __builtin_elementwise_max(h, (v2f)(0.f)); // v_pk_max_f32
        z += hr * s2[j];                                   // v_pk_fma_f32
    }
    float ga = 1.f / (1.f + expf(-z.x));
    float gb = 1.f / (1.f + expf(-z.y));
    g1[e] = ga; g2[e] = gb;
    int c = ei[NEDGES + e];
    atomicAdd(&deg1[c], ga);
    atomicAdd(&deg2[c], gb);
    atomicAdd(&cnt[c], 1);
}

// ---------------- deg -> rsqrt(deg) in place (deg >= 1 always)
__global__ void k_rsqrt(float* __restrict__ d1, float* __restrict__ d2) {
    int i = blockIdx.x * blockDim.x + threadIdx.x;
    if (i < NNODES) { d1[i] = rsqrtf(d1[i]); d2[i] = rsqrtf(d2[i]); }
}

// ---------------- scan phase 1: per-256-block exclusive scan + block sums
__global__ __launch_bounds__(256) void k_scan1(const int* __restrict__ cnt,
                                               int* __restrict__ offs,
                                               int* __restrict__ partial) {
    __shared__ int s[256];
    int t = threadIdx.x;
    int gid = blockIdx.x * 256 + t;
    int own = (gid < NNODES) ? cnt[gid] : 0;
    s[t] = own;
    __syncthreads();
    for (int off = 1; off < 256; off <<= 1) {
        int v = (t >= off) ? s[t - off] : 0;
        __syncthreads();
        s[t] += v;
        __syncthreads();
    }
    if (gid < NNODES) offs[gid] = s[t] - own;   // exclusive
    if (t == 255) partial[blockIdx.x] = s[255];
}

// ---------------- scan phase 2: single block scans the block sums (exclusive)
__global__ __launch_bounds__(512) void k_scan2(int* __restrict__ partial) {
    __shared__ int s[512];
    int t = threadIdx.x;
    int own = (t < NBLK_SCAN) ? partial[t] : 0;
    s[t] = own;
    __syncthreads();
    for (int off = 1; off < 512; off <<= 1) {
        int v = (t >= off) ? s[t - off] : 0;
        __syncthreads();
        s[t] += v;
        __syncthreads();
    }
    if (t < NBLK_SCAN) partial[t] = s[t] - own;  // exclusive
}

// ---------------- scan phase 3: add block offsets; init cursor; offs[N]=E
__global__ void k_scan3(int* __restrict__ offs, const int* __restrict__ partial,
                        int* __restrict__ cur) {
    int gid = blockIdx.x * blockDim.x + threadIdx.x;
    if (gid < NNODES) {
        int v = offs[gid] + partial[gid >> 8];
        offs[gid] = v;
        cur[gid] = v;
    }
    if (gid == 0) offs[NNODES] = NEDGES;
}

// ---------------- scatter edges into CSR slots; per-edge weights for BOTH
// layers packed in one float2 (8-B store).
__global__ __launch_bounds__(256) void k_scatter(
    const int* __restrict__ ei, const float* __restrict__ g1,
    const float* __restrict__ g2, const float* __restrict__ dinv1,
    const float* __restrict__ dinv2, int* __restrict__ cur,
    int* __restrict__ prow, float2* __restrict__ wl12) {
    int e = blockIdx.x * 256 + threadIdx.x;
    if (e >= NEDGES) return;
    int r = ei[e], c = ei[NEDGES + e];
    int pos = atomicAdd(&cur[c], 1);
    prow[pos] = r;
    float2 w;
    w.x = dinv1[r] * g1[e] * dinv1[c];
    w.y = dinv2[r] * g2[e] * dinv2[c];
    wl12[pos] = w;
}

// ---------------- fp32 GEMM: Y[M,128] = act(X)[M,128] @ W[128,128]
template <int RELU>
__global__ __launch_bounds__(256) void k_gemm(const float* __restrict__ X,
                                              const float* __restrict__ W,
                                              float* __restrict__ Y, int M) {
    __shared__ __align__(16) float sX[64 * 68];
    __shared__ __align__(16) float sW[64 * 132];
    int t = threadIdx.x;
    int row0 = blockIdx.x * 64;
    int tx = t & 15, ty = t >> 4;

    float acc[4][8];
#pragma unroll
    for (int i = 0; i < 4; i++)
#pragma unroll
        for (int j = 0; j < 8; j++) acc[i][j] = 0.f;

    for (int kt = 0; kt < 128; kt += 64) {
        for (int i = t; i < 1024; i += 256) {
            int r = i >> 4, c4 = i & 15;
            float4 v = make_float4(0.f, 0.f, 0.f, 0.f);
            if (row0 + r < M) v = ((const float4*)X)[(size_t)(row0 + r) * 32 + (kt >> 2) + c4];
            if (RELU) {
                v.x = fmaxf(v.x, 0.f); v.y = fmaxf(v.y, 0.f);
                v.z = fmaxf(v.z, 0.f); v.w = fmaxf(v.w, 0.f);
            }
            ((float4*)(sX + r * 68))[c4] = v;
        }
        for (int i = t; i < 2048; i += 256) {
            int r = i >> 5, c4 = i & 31;
            float4 v = ((const float4*)W)[(size_t)(kt + r) * 32 + c4];
            ((float4*)(sW + r * 132))[c4] = v;
        }
        __syncthreads();
#pragma unroll 8
        for (int k = 0; k < 64; k++) {
            float xv[4];
#pragma unroll
            for (int i = 0; i < 4; i++) xv[i] = sX[(ty * 4 + i) * 68 + k];
            float4 wA = *(const float4*)(sW + k * 132 + tx * 4);
            float4 wB = *(const float4*)(sW + k * 132 + 64 + tx * 4);
#pragma unroll
            for (int i = 0; i < 4; i++) {
                acc[i][0] += xv[i] * wA.x; acc[i][1] += xv[i] * wA.y;
                acc[i][2] += xv[i] * wA.z; acc[i][3] += xv[i] * wA.w;
                acc[i][4] += xv[i] * wB.x; acc[i][5] += xv[i] * wB.y;
                acc[i][6] += xv[i] * wB.z; acc[i][7] += xv[i] * wB.w;
            }
        }
        __syncthreads();
    }
#pragma unroll
    for (int i = 0; i < 4; i++) {
        int r = row0 + ty * 4 + i;
        if (r < M) {
            float4 o1 = make_float4(acc[i][0], acc[i][1], acc[i][2], acc[i][3]);
            float4 o2 = make_float4(acc[i][4], acc[i][5], acc[i][6], acc[i][7]);
            *(float4*)(Y + (size_t)r * 128 + tx * 4) = o1;
            *(float4*)(Y + (size_t)r * 128 + 64 + tx * 4) = o2;
        }
    }
}

// ---------------- CSR aggregation v2: one wave per node, TWO 32-lane groups
// process alternate edges with float4 loads (32 lanes x 16B = one 512-B row).
// Halves the edge-loop trip count and doubles memory-level parallelism at
// identical total traffic (row = 8 cache lines either way). Groups combine
// at the end via 4x shfl_xor(,32). Targets the latency-bound serial loop.
template <int LAYER>
__global__ __launch_bounds__(256) void k_aggcsr(
    const int* __restrict__ offs, const int* __restrict__ prow,
    const float2* __restrict__ wl12, const float* __restrict__ dinv,
    const float* __restrict__ h, float* __restrict__ out) {
    int node = blockIdx.x * 4 + (threadIdx.x >> 6);
    if (node >= NNODES) return;
    int lane = threadIdx.x & 63;
    int g    = lane >> 5;      // edge-parity group
    int sub  = lane & 31;      // float4 slot within the 128-dim row
    const float4* h4 = (const float4*)h;

    int beg = offs[node], end = offs[node + 1];

    float4 acc = make_float4(0.f, 0.f, 0.f, 0.f);
    if (g == 0) {
        float d = dinv[node];
        float4 hv = h4[(size_t)node * 32 + sub];
        acc.x = d * d * hv.x; acc.y = d * d * hv.y;
        acc.z = d * d * hv.z; acc.w = d * d * hv.w;
    }

    int e = beg + g;
    int    r_n = 0;
    float2 w_n = make_float2(0.f, 0.f);
    if (e < end) { r_n = prow[e]; w_n = wl12[e]; }
    for (; e < end; e += 2) {
        int    r  = r_n;
        float2 wp = w_n;
        if (e + 2 < end) { r_n = prow[e + 2]; w_n = wl12[e + 2]; }
        float w = (LAYER == 1) ? wp.x : wp.y;
        float4 v = h4[(size_t)r * 32 + sub];
        acc.x += w * v.x; acc.y += w * v.y;
        acc.z += w * v.z; acc.w += w * v.w;
    }

    // combine the two edge-parity groups (lane ^ 32 holds the partner partial)
    acc.x += __shfl_xor(acc.x, 32, 64);
    acc.y += __shfl_xor(acc.y, 32, 64);
    acc.z += __shfl_xor(acc.z, 32, 64);
    acc.w += __shfl_xor(acc.w, 32, 64);

    if (g == 0) ((float4*)out)[(size_t)node * 32 + sub] = acc;
}

extern "C" void kernel_launch(void* const* d_in, const int* in_sizes, int n_in,
                              void* d_out, int out_size, void* d_ws, size_t ws_size,
                              hipStream_t stream) {
    const float* x    = (const float*)d_in[0];
    const int*   ei   = (const int*)d_in[1];
    const float* ea   = (const float*)d_in[2];
    const float* W1   = (const float*)d_in[3];
    const float* m1w1 = (const float*)d_in[4];
    const float* m1b1 = (const float*)d_in[5];
    const float* m1w2 = (const float*)d_in[6];
    const float* m1b2 = (const float*)d_in[7];
    const float* W2   = (const float*)d_in[8];
    const float* m2w1 = (const float*)d_in[9];
    const float* m2b1 = (const float*)d_in[10];
    const float* m2w2 = (const float*)d_in[11];
    const float* m2b2 = (const float*)d_in[12];
    float* out = (float*)d_out;

    // Workspace layout: byte-identical footprint to the rounds-0..5 layout.
    float* ws    = (float*)d_ws;
    float* g1    = ws;                               // E
    float* g2    = g1 + NEDGES;                      // E
    float* deg1  = g2 + NEDGES;                      // N
    float* deg2  = deg1 + NNODES;                    // N
    float* hbuf  = deg2 + NNODES;                    // N*128
    float* aggbf = hbuf + (size_t)NNODES * 128;      // N*128
    float* wint  = aggbf + (size_t)NNODES * 128;     // 4096
    float* bw2   = wint + 4096;                      // 512
    float2* wl12 = (float2*)(bw2 + 512);             // E float2 (== old wl1+wl2)
    int*   cnt   = (int*)(wl12 + NEDGES);            // N (also cursor)
    int*   offs  = cnt + NNODES;                     // N+1
    int*   part  = offs + NNODES + 1;                // 1024
    int*   prow  = part + 1024;                      // E

    k_prep<<<18, 256, 0, stream>>>(m1w1, m2w1, m1b1, m2b1, m1w2, m2w2, wint, bw2);
    k_deg_init<<<(NNODES + 255) / 256, 256, 0, stream>>>(deg1, deg2, cnt);
    k_gates9<<<NEDGES / 512, 512, 0, stream>>>(ea, ei, wint, bw2, m1b2, m2b2,
                                               g1, g2, deg1, deg2, cnt);
    k_rsqrt<<<(NNODES + 255) / 256, 256, 0, stream>>>(deg1, deg2);

    // CSR build (graph shared by both layers)
    k_scan1<<<NBLK_SCAN, 256, 0, stream>>>(cnt, offs, part);
    k_scan2<<<1, 512, 0, stream>>>(part);
    k_scan3<<<(NNODES + 255) / 256, 256, 0, stream>>>(offs, part, cnt);
    k_scatter<<<NEDGES / 256, 256, 0, stream>>>(ei, g1, g2, deg1, deg2,
                                                cnt, prow, wl12);

    // layer 1
    k_gemm<0><<<(NNODES + 63) / 64, 256, 0, stream>>>(x, W1, hbuf, NNODES);
    k_aggcsr<1><<<(NNODES + 3) / 4, 256, 0, stream>>>(offs, prow, wl12, deg1, hbuf, aggbf);

    // layer 2 (relu fused into GEMM load)
    k_gemm<1><<<(NNODES + 63) / 64, 256, 0, stream>>>(aggbf, W2, hbuf, NNODES);
    k_aggcsr<2><<<(NNODES + 3) / 4, 256, 0, stream>>>(offs, prow, wl12, deg2, hbuf, out);
}